// Round 3
// baseline (295.943 us; speedup 1.0000x reference)
//
#include <hip/hip_runtime.h>
#include <hip/hip_bf16.h>

// BlocDiagLinear: out[b, n*128+r] = sum_c x[b, n*128+c] * blocks[n, r, c]
// 64 GEMMs M=4096 N=128 K=128, fp32 I/O, bf16 MFMA.
// R6: persistent-WG pipeline.
//  R5 post-mortem: clean traffic, occupancy 50%, but dur only 81 us with every
//  pipe <7% busy -> issue-continuity problem (one load burst + one store burst
//  per short-lived WG), plus XOR swizzle was 4 extra cyc/ds_read (2.1M conflicts)
//  vs R3 padding's 1/read.
//  Fixes:
//  (1) 512 WGs (64 nb x 8), 2/CU, ALL resident in one dispatch round. Each WG
//      stages W once, then loops 4 batch tiles with NO in-loop barriers.
//  (2) Cross-iteration prefetch: next tile's 8 float4 x-loads issued right
//      after raw->b convert -> loads in flight under ds_read+MFMA+store, always.
//  (3) LDS back to padded stride 136 (34816 B): free now (2 WGs use 70 KB of
//      160 KB; VGPR caps residency, not LDS), and 4x fewer conflict cycles
//      than the XOR swizzle.
//  #pragma unroll 1 on the tile loop: keeps ONE raw buffer (compiler cloning
//  raw across unrolled iterations would blow past 128 VGPR -> R4-style spill).

typedef __bf16 bf16_8 __attribute__((ext_vector_type(8)));
typedef __bf16 bf16_4 __attribute__((ext_vector_type(4)));
typedef float f32x4 __attribute__((ext_vector_type(4)));

#define LDS_K 136  // 272 B row stride: bank group advances by 1/row

__global__ __launch_bounds__(512, 4)
void BlocDiagLinear_kernel(const float* __restrict__ x,
                           const float* __restrict__ blocks,
                           float* __restrict__ out)
{
    __shared__ __align__(16) __bf16 ws[128 * LDS_K];  // 34816 B

    const int bid = blockIdx.x;
    const int nb  = bid & 63;     // block index — FAST index (channel balance)
    const int wgm = bid >> 6;     // 0..7: owns batch tiles wgm*4 .. wgm*4+3

    const int t    = threadIdx.x;
    const int lane = t & 63;
    const int w    = t >> 6;      // wave 0..7 -> 16-row batch group
    const int lm   = lane & 15;   // batch row within 16 (MFMA D-col)
    const int q    = lane >> 4;   // 8-col group within 32-wide K chunk

    // ---- issue tile-0 x loads first (overlap W staging latency) ----
    const float* xp = x + (size_t)(wgm * 4 * 128 + w * 16 + lm) * 8192
                        + (size_t)nb * 128 + q * 8;
    float4 raw[8];
#pragma unroll
    for (int kk = 0; kk < 4; ++kk) {
        raw[2 * kk]     = *(const float4*)(xp + kk * 32);
        raw[2 * kk + 1] = *(const float4*)(xp + kk * 32 + 4);
    }

    // ---- stage W block (128x128) fp32 -> bf16 into padded LDS, ONCE ----
    const int c4 = t & 31;
    const int r0 = t >> 5;        // 0..15
    const float* wg = blocks + (size_t)nb * 16384;
#pragma unroll
    for (int i = 0; i < 8; ++i) {
        const int row = i * 16 + r0;
        const float4 vw = *(const float4*)(wg + row * 128 + c4 * 4);
        bf16_4 bw = { (__bf16)vw.x, (__bf16)vw.y, (__bf16)vw.z, (__bf16)vw.w };
        *(bf16_4*)(ws + row * LDS_K + c4 * 4) = bw;
    }
    __syncthreads();   // the ONLY barrier; LDS read-only from here on

    float* op = out + (size_t)(wgm * 4 * 128 + w * 16 + lm) * 8192
                    + (size_t)nb * 128 + q * 4;

#pragma unroll 1
    for (int it = 0; it < 4; ++it) {
        // convert current tile (frees raw)
        bf16_8 b[4];
#pragma unroll
        for (int kk = 0; kk < 4; ++kk) {
            const float4 lo = raw[2 * kk];
            const float4 hi = raw[2 * kk + 1];
            b[kk] = (bf16_8){ (__bf16)lo.x, (__bf16)lo.y, (__bf16)lo.z, (__bf16)lo.w,
                              (__bf16)hi.x, (__bf16)hi.y, (__bf16)hi.z, (__bf16)hi.w };
        }
        // prefetch next tile: in flight during ds_read + MFMA + store below
        if (it < 3) {
            const float* pn = xp + (size_t)(it + 1) * 128 * 8192;
#pragma unroll
            for (int kk = 0; kk < 4; ++kk) {
                raw[2 * kk]     = *(const float4*)(pn + kk * 32);
                raw[2 * kk + 1] = *(const float4*)(pn + kk * 32 + 4);
            }
        }

        f32x4 acc[8];
#pragma unroll
        for (int mi = 0; mi < 8; ++mi)
            acc[mi] = (f32x4){0.f, 0.f, 0.f, 0.f};

#pragma unroll
        for (int kk = 0; kk < 4; ++kk) {
            bf16_8 a[8];
#pragma unroll
            for (int mi = 0; mi < 8; ++mi)
                a[mi] = *(const bf16_8*)(ws + (mi * 16 + lm) * LDS_K
                                            + kk * 32 + q * 8);
#pragma unroll
            for (int mi = 0; mi < 8; ++mi)
                acc[mi] = __builtin_amdgcn_mfma_f32_16x16x32_bf16(
                              a[mi], b[kk], acc[mi], 0, 0, 0);
        }

        // Epilogue: D row = q*4+reg -> r (consecutive => float4 along r)
        float* og = op + (size_t)it * 128 * 8192;
#pragma unroll
        for (int mi = 0; mi < 8; ++mi)
            *(f32x4*)(og + mi * 16) = acc[mi];
    }
}

extern "C" void kernel_launch(void* const* d_in, const int* in_sizes, int n_in,
                              void* d_out, int out_size, void* d_ws, size_t ws_size,
                              hipStream_t stream) {
    const float* x      = (const float*)d_in[0];
    const float* blocks = (const float*)d_in[1];
    float* out          = (float*)d_out;
    BlocDiagLinear_kernel<<<dim3(64 * 8), dim3(512), 0, stream>>>(x, blocks, out);
}

// Round 4
// 232.876 us; speedup vs baseline: 1.2708x; 1.2708x over previous
//
#include <hip/hip_runtime.h>
#include <hip/hip_bf16.h>

// BlocDiagLinear: out[b, n*128+r] = sum_c x[b, n*128+c] * blocks[n, r, c]
// 64 GEMMs M=4096 N=128 K=128, fp32 I/O, bf16 MFMA.
// R7: DMA-pipelined persistent WGs.
//  R4/R6 post-mortems: ANY attempt to hold in-flight x tiles in VGPRs makes
//  the allocator squeeze+spill (twice: 48 VGPR/+300MB scratch, 64 VGPR/+190MB).
//  R5 (best, 81us) is latency-bound: 16 waves/CU x 8 loads x 16B = 2KB
//  outstanding per CU << ~9KB needed (Little's law @ ~900cy HBM latency).
//  Fix: outstanding bytes move to the global_load_lds DMA queue (zero VGPR).
//  - 512 WGs (64 nb x 8 owners), 512 thr, 2 WGs/CU resident entire kernel.
//  - W staged once: bf16, padded stride 136 -> a-frag reads are bank-minimal
//    (bank group = (lm&7 + q + 4kk)&7: 8 lanes/group = b128 minimum).
//  - x: 16 chunks of 32 rows, fp32, double-buffered LDS (2x16KB), staged by
//    global_load_lds w=16. XOR swizzle via PRE-SWIZZLED GLOBAL SOURCE (linear
//    LDS dest, rule 21): 16B granule p = g ^ (row&7); read side applies same
//    XOR -> b128 reads land 8 lanes/bank-group = minimum.
//  - T3 counted-vmcnt 2-phase: s_waitcnt vmcnt(2) + raw s_barrier per chunk
//    (prefetch c_{t+1} never drained); 2nd barrier guards buffer reuse.
//  Per-wave regs: acc[2]=8 + transients ~= 45 VGPR -> nothing to spill.

typedef __bf16 bf16_8 __attribute__((ext_vector_type(8)));
typedef __bf16 bf16_4 __attribute__((ext_vector_type(4)));
typedef float f32x4 __attribute__((ext_vector_type(4)));

#define LDS_WK 136  // W row stride (bf16): 272 B

__global__ __launch_bounds__(512, 4)
void BlocDiagLinear_kernel(const float* __restrict__ x,
                           const float* __restrict__ blocks,
                           float* __restrict__ out)
{
    __shared__ __align__(16) __bf16 wlds[128 * LDS_WK];   // 34816 B
    __shared__ __align__(16) float  xlds[2][32 * 128];    // 2 x 16384 B

    const int bid = blockIdx.x;
    const int nb  = bid & 63;     // block index — FAST index (channel balance)
    const int own = bid >> 6;     // 0..7: owns batch rows [own*512, own*512+512)

    const int t    = threadIdx.x;
    const int lane = t & 63;
    const int w    = t >> 6;      // wave 0..7
    const int lm   = lane & 15;
    const int q    = lane >> 4;

    const int bg   = w & 1;       // batch 16-row group within 32-row chunk
    const int rb   = w >> 1;      // r-block 0..3 (32 r each)

    const int l5  = lane >> 5;    // 0/1 (row within staging pair)
    const int p31 = lane & 31;    // physical 16B granule within row

    // stage chunk `ch` into xlds[bufi]: wave w issues 2 DMA instrs covering
    // rows w*4 .. w*4+3; lane l -> row w*4+i*2+l5, LDS granule p31 (linear),
    // global source granule = p31 ^ (row&7)  (inverse of the read-side XOR)
#define STAGE(bufi, ch)                                                       \
    {                                                                         \
        _Pragma("unroll")                                                     \
        for (int i = 0; i < 2; ++i) {                                         \
            const int row  = w * 4 + i * 2 + l5;                              \
            const int gcol = (p31 ^ (row & 7)) * 4;                           \
            const float* src = x + (size_t)(own * 512 + (ch) * 32 + row) * 8192 \
                                 + nb * 128 + gcol;                           \
            __builtin_amdgcn_global_load_lds(                                 \
                (const __attribute__((address_space(1))) unsigned int*)src,   \
                (__attribute__((address_space(3))) unsigned int*)             \
                    (&xlds[bufi][(w * 4 + i * 2) * 128]),                     \
                16, 0, 0);                                                    \
        }                                                                     \
    }

    // ---- prologue: W reg-stage loads first (consumed early), then DMA ----
    const int c4 = t & 31;
    const int r0 = t >> 5;        // 0..15
    const float* wg = blocks + (size_t)nb * 16384;
    float4 wraw[8];
#pragma unroll
    for (int i = 0; i < 8; ++i)
        wraw[i] = *(const float4*)(wg + (i * 16 + r0) * 128 + c4 * 4);

    STAGE(0, 0);
    STAGE(1, 1);

#pragma unroll
    for (int i = 0; i < 8; ++i) {
        const int row = i * 16 + r0;
        bf16_4 bw = { (__bf16)wraw[i].x, (__bf16)wraw[i].y,
                      (__bf16)wraw[i].z, (__bf16)wraw[i].w };
        *(bf16_4*)(wlds + row * LDS_WK + c4 * 4) = bw;
    }
    asm volatile("s_waitcnt lgkmcnt(0)" ::: "memory");
    __builtin_amdgcn_sched_barrier(0);
    __builtin_amdgcn_s_barrier();   // W visible to all waves

#pragma unroll 1
    for (int ch = 0; ch < 16; ++ch) {
        const int cur = ch & 1;

        // my chunk-ch DMA retired (others' guaranteed by barrier below);
        // leaves chunk ch+1 (2 ops) in flight — never drained.
        asm volatile("s_waitcnt vmcnt(2)" ::: "memory");
        __builtin_amdgcn_sched_barrier(0);
        __builtin_amdgcn_s_barrier();
        __builtin_amdgcn_sched_barrier(0);

        f32x4 acc[2];
        acc[0] = (f32x4){0.f, 0.f, 0.f, 0.f};
        acc[1] = (f32x4){0.f, 0.f, 0.f, 0.f};

        const int xrow = bg * 16 + lm;
        const int s    = xrow & 7;    // read-side XOR (matches source pre-swz)
        const float* xr = &xlds[cur][xrow * 128];

#pragma unroll
        for (int kk = 0; kk < 4; ++kk) {
            const f32x4 lo = *(const f32x4*)(xr + (kk * 8 + ((q * 2 + 0) ^ s)) * 4);
            const f32x4 hi = *(const f32x4*)(xr + (kk * 8 + ((q * 2 + 1) ^ s)) * 4);
            const bf16_8 b = { (__bf16)lo.x, (__bf16)lo.y, (__bf16)lo.z, (__bf16)lo.w,
                               (__bf16)hi.x, (__bf16)hi.y, (__bf16)hi.z, (__bf16)hi.w };
#pragma unroll
            for (int rg = 0; rg < 2; ++rg) {
                const bf16_8 a = *(const bf16_8*)(wlds + (rb * 32 + rg * 16 + lm) * LDS_WK
                                                      + kk * 32 + q * 8);
                acc[rg] = __builtin_amdgcn_mfma_f32_16x16x32_bf16(a, b, acc[rg], 0, 0, 0);
            }
        }

        // Epilogue: D row = q*4+reg -> r (float4 along r), col = lm -> batch.
        float* og = out + (size_t)(own * 512 + ch * 32 + bg * 16 + lm) * 8192
                        + nb * 128 + rb * 32 + q * 4;
        *(f32x4*)(og)      = acc[0];
        *(f32x4*)(og + 16) = acc[1];

        // all waves done reading xlds[cur] before restaging it
        __builtin_amdgcn_sched_barrier(0);
        __builtin_amdgcn_s_barrier();
        __builtin_amdgcn_sched_barrier(0);

        if (ch + 2 < 16) STAGE(cur, ch + 2);
    }
#undef STAGE
}

extern "C" void kernel_launch(void* const* d_in, const int* in_sizes, int n_in,
                              void* d_out, int out_size, void* d_ws, size_t ws_size,
                              hipStream_t stream) {
    const float* x      = (const float*)d_in[0];
    const float* blocks = (const float*)d_in[1];
    float* out          = (float*)d_out;
    BlocDiagLinear_kernel<<<dim3(64 * 8), dim3(512), 0, stream>>>(x, blocks, out);
}